// Round 2
// baseline (818.273 us; speedup 1.0000x reference)
//
#include <hip/hip_runtime.h>

typedef __bf16 bf16x8 __attribute__((ext_vector_type(8)));
typedef float f32x4 __attribute__((ext_vector_type(4)));

#define LDK 40   // padded LDS k-stride (bf16 elems): 80 B rows, 16B-aligned
#define NB 16
#define C_ 512
#define CI 256
#define HW 4096

__device__ __forceinline__ float bf2f(unsigned short u){
  union { unsigned int u; float f; } c; c.u = ((unsigned int)u) << 16; return c.f;
}
__device__ __forceinline__ unsigned short f2bf(float f){
  union { float f; unsigned int u; } c; c.f = f;
  unsigned int u = c.u + 0x7fffu + ((c.u >> 16) & 1u);
  return (unsigned short)(u >> 16);
}
__device__ __forceinline__ float read_val(const void* p, int i, bool f32){
  return f32 ? ((const float*)p)[i] : bf2f(((const unsigned short*)p)[i]);
}

// ---- staging helpers (256 threads) ----

// 128 rows x 32 k bf16 row-major -> LDS [row][k]
__device__ __forceinline__ void stage_rm(const unsigned short* __restrict__ src, int stride,
                                         unsigned short* dst, int t){
  #pragma unroll
  for (int it = 0; it < 2; ++it){
    int idx = t + it*256;
    int row = idx >> 2;
    int ko  = (idx & 3) * 8;
    *(uint4*)(dst + row*LDK + ko) = *(const uint4*)(src + (size_t)row*stride + ko);
  }
}

// 128 rows x 32 k fp32 row-major -> split hi/lo bf16 LDS tiles
__device__ __forceinline__ void stage_rm_f32(const float* __restrict__ src, int stride,
                                             unsigned short* dh, unsigned short* dl, int t){
  #pragma unroll
  for (int it = 0; it < 4; ++it){
    int idx = t + it*256;            // 0..1023
    int row = idx >> 3;
    int ko  = (idx & 7) * 4;
    f32x4 v = *(const f32x4*)(src + (size_t)row*stride + ko);
    #pragma unroll
    for (int e = 0; e < 4; ++e){
      float fv = v[e];
      unsigned short h = f2bf(fv);
      dh[row*LDK + ko + e] = h;
      dl[row*LDK + ko + e] = f2bf(fv - bf2f(h));
    }
  }
}

// 32 src-rows x 128 src-cols bf16 -> LDS transposed dst[col][row]
__device__ __forceinline__ void stage_tr(const unsigned short* __restrict__ src, int stride,
                                         unsigned short* dst, int t){
  #pragma unroll
  for (int it = 0; it < 2; ++it){
    int idx = t + it*256;
    int row = idx >> 4;              // 0..31
    int co  = (idx & 15) * 8;
    uint4 vv = *(const uint4*)(src + (size_t)row*stride + co);
    unsigned short e[8]; *(uint4*)e = vv;
    #pragma unroll
    for (int k = 0; k < 8; ++k) dst[(co + k)*LDK + row] = e[k];
  }
}

// 32 src-rows x 128 src-cols fp32 -> LDS transposed (hi bf16 only)
__device__ __forceinline__ void stage_tr_f32(const float* __restrict__ src, int stride,
                                             unsigned short* dst, int t){
  #pragma unroll
  for (int it = 0; it < 2; ++it){
    int idx = t + it*256;
    int row = idx >> 4;              // 0..31
    int co  = (idx & 15) * 8;
    f32x4 v0 = *(const f32x4*)(src + (size_t)row*stride + co);
    f32x4 v1 = *(const f32x4*)(src + (size_t)row*stride + co + 4);
    #pragma unroll
    for (int k = 0; k < 4; ++k){
      dst[(co + k)*LDK + row]     = f2bf(v0[k]);
      dst[(co + 4 + k)*LDK + row] = f2bf(v1[k]);
    }
  }
}

// 128 rows x 32 k fp32 -> hi/lo bf16 (used for G)
__device__ __forceinline__ void stage_split(const float* __restrict__ src, int stride,
                                            unsigned short* dh, unsigned short* dl, int t){
  stage_rm_f32(src, stride, dh, dl, t);
}

// one 32-wide k-step: wave (wm,wn) covers 64x64, 16 mfma
__device__ __forceinline__ void mfma_step(const unsigned short* As, const unsigned short* Bs,
                                          f32x4 acc[4][4], int wm, int wn, int lane){
  const int r = lane & 15, q = lane >> 4;
  bf16x8 a[4], b[4];
  #pragma unroll
  for (int i = 0; i < 4; ++i)
    a[i] = *(const bf16x8*)(As + (wm*64 + 16*i + r)*LDK + 8*q);
  #pragma unroll
  for (int j = 0; j < 4; ++j)
    b[j] = *(const bf16x8*)(Bs + (wn*64 + 16*j + r)*LDK + 8*q);
  #pragma unroll
  for (int i = 0; i < 4; ++i)
    #pragma unroll
    for (int j = 0; j < 4; ++j)
      acc[i][j] = __builtin_amdgcn_mfma_f32_16x16x32_bf16(a[i], b[j], acc[i][j], 0, 0, 0);
}

// ---- K0: dtype detect. fp32 inputs read as bf16 halves contain exp==0xFF patterns.
__global__ __launch_bounds__(256) void k_detect(const unsigned short* __restrict__ x, int* flag){
  const int t = threadIdx.x;
  int cnt = 0;
  for (int i = t; i < 65536; i += 256){
    unsigned short u = x[i];
    if (((u >> 7) & 0xFF) == 0xFF) cnt++;
  }
  __shared__ int red[256];
  red[t] = cnt; __syncthreads();
  for (int s2 = 128; s2 > 0; s2 >>= 1){
    if (t < s2) red[t] += red[t + s2];
    __syncthreads();
  }
  if (t == 0) flag[0] = (red[0] > 0) ? 1 : 0;
}

// ---- K0b: convert weights to canonical buffers (theta/phi split hi/lo; g/W hi; biases fp32)
__global__ __launch_bounds__(256) void k_wconv(const void* tw, const void* pw, const void* gw,
    const void* Ww, const void* gb, const void* tb, const void* pb, const void* Wb,
    const void* gam, const void* bet, const int* __restrict__ flag,
    unsigned short* twh, unsigned short* twl, unsigned short* phh, unsigned short* phl,
    unsigned short* gwc, unsigned short* Wwc, float* biasf){
  const bool f32 = (*flag != 0);
  const int bid = blockIdx.x, t = threadIdx.x;
  if (bid < 2048){
    const int seg = bid >> 9;
    const int i = (bid & 511)*256 + t;
    if (seg == 0){
      float w = read_val(tw, i, f32);
      unsigned short h = f2bf(w);
      twh[i] = h; twl[i] = f2bf(w - bf2f(h));
    } else if (seg == 1){
      float w = read_val(pw, i, f32);
      unsigned short h = f2bf(w);
      phh[i] = h; phl[i] = f2bf(w - bf2f(h));
    } else if (seg == 2){
      gwc[i] = f2bf(read_val(gw, i, f32));
    } else {
      Wwc[i] = f2bf(read_val(Ww, i, f32));
    }
  } else {
    const int i = (bid - 2048)*256 + t;
    if (i < 2304){
      float v;
      if      (i <  256) v = read_val(gb,  i,        f32);
      else if (i <  512) v = read_val(tb,  i - 256,  f32);
      else if (i <  768) v = read_val(pb,  i - 512,  f32);
      else if (i < 1280) v = read_val(Wb,  i - 768,  f32);
      else if (i < 1792) v = read_val(gam, i - 1280, f32);
      else               v = read_val(bet, i - 1792, f32);
      biasf[i] = v;
    }
  }
}

// ---- K1a: G[b] = x[b] x[b]^T (fp32 exact via hi/lo split), s[b] = rowsum(x[b])
__global__ __launch_bounds__(256) void k_gram(const void* __restrict__ xraw,
                                              const int* __restrict__ flag,
                                              float* __restrict__ G, float* __restrict__ s){
  const bool f32 = (*flag != 0);
  const int b = blockIdx.z, bn = blockIdx.x, bm = blockIdx.y;
  const int t = threadIdx.x, lane = t & 63, w = t >> 6, wm = w >> 1, wn = w & 1;
  __shared__ unsigned short Ah[128*LDK];
  __shared__ unsigned short Al[128*LDK];
  __shared__ unsigned short Bh[128*LDK];
  __shared__ unsigned short Bl[128*LDK];
  __shared__ float red[256];
  f32x4 acc[4][4] = {};
  float sacc = 0.f;
  const bool diag = (bm == bn);
  for (int k0 = 0; k0 < HW; k0 += 32){
    if (f32){
      const float* xb = (const float*)xraw + (size_t)b*C_*HW;
      stage_rm_f32(xb + (size_t)bm*128*HW + k0, HW, Ah, Al, t);
      if (!diag) stage_rm_f32(xb + (size_t)bn*128*HW + k0, HW, Bh, Bl, t);
    } else {
      const unsigned short* xb = (const unsigned short*)xraw + (size_t)b*C_*HW;
      stage_rm(xb + (size_t)bm*128*HW + k0, HW, Ah, t);
      if (!diag) stage_rm(xb + (size_t)bn*128*HW + k0, HW, Bh, t);
    }
    __syncthreads();
    const unsigned short* BhU = diag ? Ah : Bh;
    const unsigned short* BlU = diag ? Al : Bl;
    mfma_step(Ah, BhU, acc, wm, wn, lane);
    if (f32){
      mfma_step(Ah, BlU, acc, wm, wn, lane);   // xh·xl^T
      mfma_step(Al, BhU, acc, wm, wn, lane);   // xl·xh^T
    }
    if (diag){
      const int row = t >> 1, half = t & 1;
      const unsigned short* ph = Ah + row*LDK + half*16;
      const unsigned short* pl = Al + row*LDK + half*16;
      if (f32){
        #pragma unroll
        for (int e = 0; e < 16; ++e) sacc += bf2f(ph[e]) + bf2f(pl[e]);
      } else {
        #pragma unroll
        for (int e = 0; e < 16; ++e) sacc += bf2f(ph[e]);
      }
    }
    __syncthreads();
  }
  float* Gb = G + (size_t)b*C_*C_;
  const int r = lane & 15, q = lane >> 4;
  #pragma unroll
  for (int i = 0; i < 4; ++i)
    #pragma unroll
    for (int j = 0; j < 4; ++j)
      #pragma unroll
      for (int ii = 0; ii < 4; ++ii){
        int row = bm*128 + wm*64 + 16*i + 4*q + ii;
        int col = bn*128 + wn*64 + 16*j + r;
        Gb[(size_t)row*C_ + col] = acc[i][j][ii];
      }
  if (diag){
    red[t] = sacc;
    __syncthreads();
    if (t < 128) s[(size_t)b*C_ + bm*128 + t] = red[2*t] + red[2*t+1];
  }
}

// ---- K1b: gT[b] (4096x256) = x^T gw^T + g_b
__global__ __launch_bounds__(256) void k_gconv(const void* __restrict__ xraw,
    const int* __restrict__ flag, const unsigned short* __restrict__ gwc,
    const float* __restrict__ gbf, unsigned short* __restrict__ gT){
  const bool f32 = (*flag != 0);
  const int b = blockIdx.z, mt = blockIdx.x, nt = blockIdx.y;
  const int t = threadIdx.x, lane = t & 63, w = t >> 6, wm = w >> 1, wn = w & 1;
  __shared__ unsigned short As[128*LDK];
  __shared__ unsigned short Bs[128*LDK];
  f32x4 acc[4][4] = {};
  for (int k0 = 0; k0 < C_; k0 += 32){
    if (f32){
      const float* xb = (const float*)xraw + (size_t)b*C_*HW;
      stage_tr_f32(xb + (size_t)k0*HW + mt*128, HW, As, t);
    } else {
      const unsigned short* xb = (const unsigned short*)xraw + (size_t)b*C_*HW;
      stage_tr(xb + (size_t)k0*HW + mt*128, HW, As, t);
    }
    stage_rm(gwc + (size_t)nt*128*C_ + k0, C_, Bs, t);
    __syncthreads();
    mfma_step(As, Bs, acc, wm, wn, lane);
    __syncthreads();
  }
  unsigned short* gTb = gT + (size_t)b*HW*CI;
  const int r = lane & 15, q = lane >> 4;
  #pragma unroll
  for (int j = 0; j < 4; ++j){
    int col = nt*128 + wn*64 + 16*j + r;
    float bias = gbf[col];
    #pragma unroll
    for (int i = 0; i < 4; ++i)
      #pragma unroll
      for (int ii = 0; ii < 4; ++ii){
        int row = mt*128 + wm*64 + 16*i + 4*q + ii;
        gTb[(size_t)row*CI + col] = f2bf(acc[i][j][ii] + bias);
      }
  }
}

// ---- K2: T[b] = theta_w @ G[b]   (theta split, G split; G symmetric -> row reads)
__global__ __launch_bounds__(256) void k_T(const unsigned short* __restrict__ twh,
    const unsigned short* __restrict__ twl, const int* __restrict__ flag,
    const float* __restrict__ G, unsigned short* __restrict__ Th, unsigned short* __restrict__ Tl){
  const bool f32 = (*flag != 0);
  const int b = blockIdx.z, nt = blockIdx.x, mt = blockIdx.y;
  const int t = threadIdx.x, lane = t & 63, w = t >> 6, wm = w >> 1, wn = w & 1;
  __shared__ unsigned short Ath[128*LDK];
  __shared__ unsigned short Atl[128*LDK];
  __shared__ unsigned short Bh[128*LDK];
  __shared__ unsigned short Bl[128*LDK];
  const float* Gb = G + (size_t)b*C_*C_;
  f32x4 acc[4][4] = {};
  for (int k0 = 0; k0 < C_; k0 += 32){
    stage_rm(twh + (size_t)mt*128*C_ + k0, C_, Ath, t);
    if (f32) stage_rm(twl + (size_t)mt*128*C_ + k0, C_, Atl, t);
    stage_split(Gb + (size_t)nt*128*C_ + k0, C_, Bh, Bl, t);
    __syncthreads();
    mfma_step(Ath, Bh, acc, wm, wn, lane);
    mfma_step(Ath, Bl, acc, wm, wn, lane);
    if (f32) mfma_step(Atl, Bh, acc, wm, wn, lane);
    __syncthreads();
  }
  unsigned short* Thb = Th + (size_t)b*CI*C_;
  unsigned short* Tlb = Tl + (size_t)b*CI*C_;
  const int r = lane & 15, q = lane >> 4;
  #pragma unroll
  for (int i = 0; i < 4; ++i)
    #pragma unroll
    for (int j = 0; j < 4; ++j)
      #pragma unroll
      for (int ii = 0; ii < 4; ++ii){
        int row = mt*128 + wm*64 + 16*i + 4*q + ii;
        int col = nt*128 + wn*64 + 16*j + r;
        float vv = acc[i][j][ii];
        unsigned short h = f2bf(vv);
        Thb[(size_t)row*C_ + col] = h;
        Tlb[(size_t)row*C_ + col] = f2bf(vv - bf2f(h));
      }
}

// ---- K3: f[b] = (Th+Tl) @ phi^T  with phi split
__global__ __launch_bounds__(256) void k_f(const unsigned short* __restrict__ Th,
    const unsigned short* __restrict__ Tl, const unsigned short* __restrict__ phh,
    const unsigned short* __restrict__ phl, const int* __restrict__ flag,
    float* __restrict__ f){
  const bool f32 = (*flag != 0);
  const int b = blockIdx.z, nt = blockIdx.x, mt = blockIdx.y;
  const int t = threadIdx.x, lane = t & 63, w = t >> 6, wm = w >> 1, wn = w & 1;
  __shared__ unsigned short ATh[128*LDK];
  __shared__ unsigned short ATl[128*LDK];
  __shared__ unsigned short Bph[128*LDK];
  __shared__ unsigned short Bpl[128*LDK];
  f32x4 acc[4][4] = {};
  const unsigned short* Thb = Th + (size_t)b*CI*C_;
  const unsigned short* Tlb = Tl + (size_t)b*CI*C_;
  for (int k0 = 0; k0 < C_; k0 += 32){
    stage_rm(Thb + (size_t)mt*128*C_ + k0, C_, ATh, t);
    stage_rm(Tlb + (size_t)mt*128*C_ + k0, C_, ATl, t);
    stage_rm(phh + (size_t)nt*128*C_ + k0, C_, Bph, t);
    if (f32) stage_rm(phl + (size_t)nt*128*C_ + k0, C_, Bpl, t);
    __syncthreads();
    mfma_step(ATh, Bph, acc, wm, wn, lane);
    mfma_step(ATl, Bph, acc, wm, wn, lane);
    if (f32) mfma_step(ATh, Bpl, acc, wm, wn, lane);
    __syncthreads();
  }
  float* fb = f + (size_t)b*CI*CI;
  const int r = lane & 15, q = lane >> 4;
  #pragma unroll
  for (int i = 0; i < 4; ++i)
    #pragma unroll
    for (int j = 0; j < 4; ++j)
      #pragma unroll
      for (int ii = 0; ii < 4; ++ii){
        int row = mt*128 + wm*64 + 16*i + 4*q + ii;
        int col = nt*128 + wn*64 + 16*j + r;
        fb[(size_t)row*CI + col] = acc[i][j][ii];
      }
}

// u = theta_w @ s, v = phi_w @ s
__global__ __launch_bounds__(256) void k_uv(const unsigned short* __restrict__ twh,
    const unsigned short* __restrict__ twl, const unsigned short* __restrict__ phh,
    const unsigned short* __restrict__ phl, const float* __restrict__ s,
    float* __restrict__ u, float* __restrict__ v){
  const int b = blockIdx.x, c = threadIdx.x;
  __shared__ float sl[C_];
  sl[c] = s[(size_t)b*C_ + c];
  sl[c + 256] = s[(size_t)b*C_ + c + 256];
  __syncthreads();
  float su = 0.f, sv = 0.f;
  for (int e = 0; e < C_; ++e){
    su += (bf2f(twh[(size_t)c*C_ + e]) + bf2f(twl[(size_t)c*C_ + e])) * sl[e];
    sv += (bf2f(phh[(size_t)c*C_ + e]) + bf2f(phl[(size_t)c*C_ + e])) * sl[e];
  }
  u[(size_t)b*CI + c] = su;
  v[(size_t)b*CI + c] = sv;
}

// ---- K4: softmax rows of f (+ rank-1 bias corrections), write S bf16
__global__ __launch_bounds__(256) void k_softmax(const float* __restrict__ f,
    const float* __restrict__ u, const float* __restrict__ v,
    const float* __restrict__ tbf, const float* __restrict__ pbf,
    unsigned short* __restrict__ S){
  const int b = blockIdx.y;
  const int c = blockIdx.x*4 + (threadIdx.x >> 6);
  const int lane = threadIdx.x & 63;
  const float* fr = f + ((size_t)b*CI + c)*CI;
  f32x4 val = *(const f32x4*)(fr + lane*4);
  const float uc = u[(size_t)b*CI + c];
  const float tbc = tbf[c];
  float vv[4];
  #pragma unroll
  for (int k = 0; k < 4; ++k){
    int d = lane*4 + k;
    float pbd = pbf[d];
    vv[k] = val[k] + uc*pbd + tbc*(v[(size_t)b*CI + d] + 4096.0f*pbd);
  }
  float mx = fmaxf(fmaxf(vv[0], vv[1]), fmaxf(vv[2], vv[3]));
  #pragma unroll
  for (int off = 1; off < 64; off <<= 1) mx = fmaxf(mx, __shfl_xor(mx, off));
  float e[4], sum = 0.f;
  #pragma unroll
  for (int k = 0; k < 4; ++k){ e[k] = expf(vv[k] - mx); sum += e[k]; }
  #pragma unroll
  for (int off = 1; off < 64; off <<= 1) sum += __shfl_xor(sum, off);
  float inv = 1.0f / sum;
  uint2 pack;
  pack.x = (unsigned int)f2bf(e[0]*inv) | ((unsigned int)f2bf(e[1]*inv) << 16);
  pack.y = (unsigned int)f2bf(e[2]*inv) | ((unsigned int)f2bf(e[3]*inv) << 16);
  *(uint2*)(S + ((size_t)b*CI + c)*CI + lane*4) = pack;
}

// ---- K5: M2[b] = W_w @ S[b]
__global__ __launch_bounds__(256) void k_M2(const unsigned short* __restrict__ Wwc,
                                            const unsigned short* __restrict__ S,
                                            unsigned short* __restrict__ M2){
  const int b = blockIdx.z, nt = blockIdx.x, mt = blockIdx.y;
  const int t = threadIdx.x, lane = t & 63, w = t >> 6, wm = w >> 1, wn = w & 1;
  __shared__ unsigned short As[128*LDK];
  __shared__ unsigned short Bs[128*LDK];
  f32x4 acc[4][4] = {};
  for (int k0 = 0; k0 < CI; k0 += 32){
    stage_rm(Wwc + (size_t)mt*128*CI + k0, CI, As, t);
    stage_tr(S + (size_t)b*CI*CI + (size_t)k0*CI + nt*128, CI, Bs, t);
    __syncthreads();
    mfma_step(As, Bs, acc, wm, wn, lane);
    __syncthreads();
  }
  unsigned short* M2b = M2 + (size_t)b*C_*CI;
  const int r = lane & 15, q = lane >> 4;
  #pragma unroll
  for (int i = 0; i < 4; ++i)
    #pragma unroll
    for (int j = 0; j < 4; ++j)
      #pragma unroll
      for (int ii = 0; ii < 4; ++ii){
        int row = mt*128 + wm*64 + 16*i + 4*q + ii;
        int col = nt*128 + wn*64 + 16*j + r;
        M2b[(size_t)row*CI + col] = f2bf(acc[i][j][ii]);
      }
}

// ---- K6: z[b] = M2[b] @ g[b] + W_b
__global__ __launch_bounds__(256) void k_z(const unsigned short* __restrict__ M2,
                                           const unsigned short* __restrict__ gT,
                                           const float* __restrict__ Wbf,
                                           unsigned short* __restrict__ z){
  const int b = blockIdx.z, nt = blockIdx.x, mt = blockIdx.y;
  const int t = threadIdx.x, lane = t & 63, w = t >> 6, wm = w >> 1, wn = w & 1;
  __shared__ unsigned short As[128*LDK];
  __shared__ unsigned short Bs[128*LDK];
  const unsigned short* M2b = M2 + (size_t)b*C_*CI;
  const unsigned short* gTb = gT + (size_t)b*HW*CI;
  f32x4 acc[4][4] = {};
  for (int k0 = 0; k0 < CI; k0 += 32){
    stage_rm(M2b + (size_t)mt*128*CI + k0, CI, As, t);
    stage_rm(gTb + (size_t)nt*128*CI + k0, CI, Bs, t);
    __syncthreads();
    mfma_step(As, Bs, acc, wm, wn, lane);
    __syncthreads();
  }
  unsigned short* zb = z + (size_t)b*C_*HW;
  const int r = lane & 15, q = lane >> 4;
  #pragma unroll
  for (int i = 0; i < 4; ++i)
    #pragma unroll
    for (int ii = 0; ii < 4; ++ii){
      int row = mt*128 + wm*64 + 16*i + 4*q + ii;
      float bias = Wbf[row];
      #pragma unroll
      for (int j = 0; j < 4; ++j){
        int col = nt*128 + wn*64 + 16*j + r;
        zb[(size_t)row*HW + col] = f2bf(acc[i][j][ii] + bias);
      }
    }
}

// ---- K7: per-channel BN stats -> scale/shift
__global__ __launch_bounds__(256) void k_bnstats(const unsigned short* __restrict__ z,
    const float* __restrict__ gamf, const float* __restrict__ betf,
    float* __restrict__ scale, float* __restrict__ shift){
  const int o = blockIdx.x, t = threadIdx.x, lane = t & 63, w = t >> 6;
  float sum = 0.f, ss = 0.f;
  for (int b = 0; b < NB; ++b){
    const unsigned short* p = z + ((size_t)b*C_ + o)*HW + t*16;
    #pragma unroll
    for (int it = 0; it < 2; ++it){
      uint4 raw = *(const uint4*)(p + it*8);
      unsigned int wd[4] = {raw.x, raw.y, raw.z, raw.w};
      #pragma unroll
      for (int k = 0; k < 4; ++k){
        float f0 = bf2f((unsigned short)(wd[k] & 0xffff));
        float f1 = bf2f((unsigned short)(wd[k] >> 16));
        sum += f0 + f1; ss += f0*f0 + f1*f1;
      }
    }
  }
  #pragma unroll
  for (int off = 1; off < 64; off <<= 1){
    sum += __shfl_xor(sum, off);
    ss  += __shfl_xor(ss, off);
  }
  __shared__ float r1[4], r2[4];
  if (lane == 0){ r1[w] = sum; r2[w] = ss; }
  __syncthreads();
  if (t == 0){
    float S1 = r1[0]+r1[1]+r1[2]+r1[3];
    float S2 = r2[0]+r2[1]+r2[2]+r2[3];
    const float n = (float)NB * (float)HW;
    float mean = S1 / n;
    float var  = S2 / n - mean*mean;
    float sc = gamf[o] * rsqrtf(var + 1e-5f);
    scale[o] = sc;
    shift[o] = betf[o] - mean*sc;
  }
}

// ---- K8: out = z*scale + shift + x  (dtype per flag)
__global__ __launch_bounds__(256) void k_out(const unsigned short* __restrict__ z,
    const void* __restrict__ xraw, const int* __restrict__ flag,
    const float* __restrict__ scale, const float* __restrict__ shift, void* __restrict__ outraw){
  const bool f32 = (*flag != 0);
  const size_t g = (size_t)blockIdx.x*256 + threadIdx.x;
  const size_t base = g*8;
  const int o = (int)((base >> 12) & (C_ - 1));
  const float sc = scale[o], sh = shift[o];
  uint4 zr = *(const uint4*)(z + base);
  unsigned int zz[4] = {zr.x, zr.y, zr.z, zr.w};
  float zv[8];
  #pragma unroll
  for (int k = 0; k < 4; ++k){
    zv[2*k]   = bf2f((unsigned short)(zz[k] & 0xffff));
    zv[2*k+1] = bf2f((unsigned short)(zz[k] >> 16));
  }
  if (f32){
    const float* x = (const float*)xraw;
    float* out = (float*)outraw;
    f32x4 x0 = *(const f32x4*)(x + base);
    f32x4 x1 = *(const f32x4*)(x + base + 4);
    f32x4 o0, o1;
    #pragma unroll
    for (int k = 0; k < 4; ++k){
      o0[k] = zv[k]*sc + sh + x0[k];
      o1[k] = zv[4+k]*sc + sh + x1[k];
    }
    *(f32x4*)(out + base) = o0;
    *(f32x4*)(out + base + 4) = o1;
  } else {
    const unsigned short* x = (const unsigned short*)xraw;
    unsigned short* out = (unsigned short*)outraw;
    uint4 xr = *(const uint4*)(x + base);
    unsigned int xx[4] = {xr.x, xr.y, xr.z, xr.w};
    unsigned int res[4];
    #pragma unroll
    for (int k = 0; k < 4; ++k){
      float x0 = bf2f((unsigned short)(xx[k] & 0xffff));
      float x1 = bf2f((unsigned short)(xx[k] >> 16));
      res[k] = (unsigned int)f2bf(zv[2*k]*sc + sh + x0)
             | ((unsigned int)f2bf(zv[2*k+1]*sc + sh + x1) << 16);
    }
    uint4 ov; ov.x = res[0]; ov.y = res[1]; ov.z = res[2]; ov.w = res[3];
    *(uint4*)(out + base) = ov;
  }
}

extern "C" void kernel_launch(void* const* d_in, const int* in_sizes, int n_in,
                              void* d_out, int out_size, void* d_ws, size_t ws_size,
                              hipStream_t stream){
  (void)in_sizes; (void)n_in; (void)out_size;
  const void* x   = d_in[0];
  const void* g_w = d_in[1];
  const void* g_b = d_in[2];
  const void* t_w = d_in[3];
  const void* t_b = d_in[4];
  const void* p_w = d_in[5];
  const void* p_b = d_in[6];
  const void* W_w = d_in[7];
  const void* W_b = d_in[8];
  const void* gam = d_in[9];
  const void* bet = d_in[10];
  char* ws = (char*)d_ws;

  constexpr size_t OFF_FLAG = 0;
  constexpr size_t OFF_TWH = OFF_FLAG + 16;
  constexpr size_t OFF_TWL = OFF_TWH + (size_t)CI*C_*2;
  constexpr size_t OFF_PHH = OFF_TWL + (size_t)CI*C_*2;
  constexpr size_t OFF_PHL = OFF_PHH + (size_t)CI*C_*2;
  constexpr size_t OFF_GWC = OFF_PHL + (size_t)CI*C_*2;
  constexpr size_t OFF_WWC = OFF_GWC + (size_t)CI*C_*2;
  constexpr size_t OFF_BIA = OFF_WWC + (size_t)C_*CI*2;
  constexpr size_t OFF_G  = OFF_BIA + 2304*4;
  constexpr size_t OFF_S  = OFF_G  + (size_t)NB*C_*C_*4;
  constexpr size_t OFF_U  = OFF_S  + (size_t)NB*C_*4;
  constexpr size_t OFF_V  = OFF_U  + (size_t)NB*CI*4;
  constexpr size_t OFF_GT = OFF_V  + (size_t)NB*CI*4;
  constexpr size_t OFF_TH = OFF_GT + (size_t)NB*HW*CI*2;
  constexpr size_t OFF_TL = OFF_TH + (size_t)NB*CI*C_*2;
  constexpr size_t OFF_F  = OFF_TL + (size_t)NB*CI*C_*2;
  constexpr size_t OFF_SM = OFF_F  + (size_t)NB*CI*CI*4;
  constexpr size_t OFF_M2 = OFF_SM + (size_t)NB*CI*CI*2;
  constexpr size_t OFF_Z  = OFF_M2 + (size_t)NB*C_*CI*2;
  constexpr size_t OFF_SC = OFF_Z  + (size_t)NB*C_*HW*2;
  constexpr size_t OFF_SH = OFF_SC + (size_t)C_*4;
  constexpr size_t TOTAL  = OFF_SH + (size_t)C_*4;
  if (ws_size < TOTAL) return;

  int* flag = (int*)(ws + OFF_FLAG);
  unsigned short* twh = (unsigned short*)(ws + OFF_TWH);
  unsigned short* twl = (unsigned short*)(ws + OFF_TWL);
  unsigned short* phh = (unsigned short*)(ws + OFF_PHH);
  unsigned short* phl = (unsigned short*)(ws + OFF_PHL);
  unsigned short* gwc = (unsigned short*)(ws + OFF_GWC);
  unsigned short* Wwc = (unsigned short*)(ws + OFF_WWC);
  float* biasf = (float*)(ws + OFF_BIA);
  float* G  = (float*)(ws + OFF_G);
  float* s  = (float*)(ws + OFF_S);
  float* u  = (float*)(ws + OFF_U);
  float* v  = (float*)(ws + OFF_V);
  unsigned short* gT = (unsigned short*)(ws + OFF_GT);
  unsigned short* Th = (unsigned short*)(ws + OFF_TH);
  unsigned short* Tl = (unsigned short*)(ws + OFF_TL);
  float* f  = (float*)(ws + OFF_F);
  unsigned short* Sm = (unsigned short*)(ws + OFF_SM);
  unsigned short* M2 = (unsigned short*)(ws + OFF_M2);
  unsigned short* z  = (unsigned short*)(ws + OFF_Z);
  float* scale = (float*)(ws + OFF_SC);
  float* shift = (float*)(ws + OFF_SH);

  float* gbf = biasf;          // 256
  float* tbf = biasf + 256;    // 256
  float* pbf = biasf + 512;    // 256
  float* Wbf = biasf + 768;    // 512
  float* gamf = biasf + 1280;  // 512
  float* betf = biasf + 1792;  // 512

  dim3 blk(256);
  k_detect <<<dim3(1),         blk, 0, stream>>>((const unsigned short*)x, flag);
  k_wconv  <<<dim3(2057),      blk, 0, stream>>>(t_w, p_w, g_w, W_w, g_b, t_b, p_b, W_b,
                                                 gam, bet, flag, twh, twl, phh, phl, gwc, Wwc, biasf);
  k_gram   <<<dim3(4, 4, NB),  blk, 0, stream>>>(x, flag, G, s);
  k_gconv  <<<dim3(32, 2, NB), blk, 0, stream>>>(x, flag, gwc, gbf, gT);
  k_T      <<<dim3(4, 2, NB),  blk, 0, stream>>>(twh, twl, flag, G, Th, Tl);
  k_uv     <<<dim3(NB),        blk, 0, stream>>>(twh, twl, phh, phl, s, u, v);
  k_f      <<<dim3(2, 2, NB),  blk, 0, stream>>>(Th, Tl, phh, phl, flag, f);
  k_softmax<<<dim3(64, NB),    blk, 0, stream>>>(f, u, v, tbf, pbf, Sm);
  k_M2     <<<dim3(2, 4, NB),  blk, 0, stream>>>(Wwc, Sm, M2);
  k_z      <<<dim3(32, 4, NB), blk, 0, stream>>>(M2, gT, Wbf, z);
  k_bnstats<<<dim3(C_),        blk, 0, stream>>>(z, gamf, betf, scale, shift);
  k_out    <<<dim3(16384),     blk, 0, stream>>>(z, x, flag, scale, shift, d_out);
}